// Round 14
// baseline (1679.233 us; speedup 1.0000x reference)
//
#include <hip/hip_runtime.h>

// LSTM 2-layer fused persistent kernel — MFMA fp16 2-term N-packed, fp32 I/O.
// R14 change vs R13 (1,550us anchor): LAYER-PIPELINED PAIRS. L1 lags L0 by
// one chunk (TC=8): pair-step {L0 step t of chunk ch} + {L1 step t of chunk
// ch-1} are independent -> ONE barrier per pair, chains overlap (L0 epilogue
// VALU || L1 MFMA). Serial barrier count 2048 -> 129*8 = 1,032. xp1 still
// batch-projected per chunk from prev chunk's h0 history (lag = TC).
// Weight residency (256KB total Whh, can't fit 8x128-reg VGPR file):
//   Whh0: 16 frags/wave in VGPR (per-chunk reload from ws, KEEP-pinned)
//   Whh1: 15 frags/wave in LDS (staged once; lane-consecutive b128 =
//         conflict-free) + frag(t4=0,s=0) in VGPR.
// LDS: Wl1 122,880 + xp0/xp1 f32 2x16,384 + h0 hist 2x2,304 + h1 ring
// 2x512 = 161,280 B < 160KiB. Serial VGPR peak ~126 (sched_barrier caps
// L1-frag inflight to 1 slice). TC=8; x read from global in proj (xc
// dropped); bias read from global in proj epilogue (bias LDS dropped).
// All R13-proven pieces kept: N-packed hi/lo (even/odd cols), gate-major
// ownership, wave-local c-update via shfl, extract trees, grant law
// (512 thr -> 128 VGPR), pack_w unchanged.
// d_ws requirement: 458,752 B.

typedef __attribute__((ext_vector_type(4))) float f32x4;
typedef _Float16 f16x8 __attribute__((ext_vector_type(8)));

#define NB   256
#define TSEQ 1024
#define II   64
#define HH   128
#define G4   512
#define TC   8
#define NCH  (TSEQ/TC)      // 128
#define SCL  0.0009765625f  // 2^-10
#define SCLI 1024.f         // 2^10

// d_ws frag regions (16B units). idx = region + ((w*4+t4)*NKS+s)*64 + lane.
#define F_WHH0  0
#define F_WHH1  8192
#define F_WIH1  16384
#define F_WIH0  24576
#define F_TOTAL 28672   // *16B = 458,752 B

#define KEEP4I(v) asm volatile("" : "+v"((v).x), "+v"((v).y), "+v"((v).z), "+v"((v).w))

__device__ __forceinline__ float tanh_f(float x){
    float ax = fabsf(x);
    float e  = __expf(2.f*ax);
    float t  = 1.f - 2.f*__builtin_amdgcn_rcpf(e + 1.f);
    return copysignf(t, x);
}
__device__ __forceinline__ f32x4 mfma16(int4 a, f16x8 b, f32x4 c){
    return __builtin_amdgcn_mfma_f32_16x16x32_f16(
        __builtin_bit_cast(f16x8, a), b, c, 0, 0, 0);
}
__device__ __forceinline__ f16x8 ldb(const _Float16* p){
    return __builtin_bit_cast(f16x8, *(const int4*)p);
}

// ---------------- pack kernel: fp32 weights -> fp16 A-fragments ------------
// Gate-major row map: fragment (w, t4, s, lane) holds
// row = t4*128 + w*16 + (lane&15), k = s*32 + (lane>>4)*8 + j.  (R13-proven)
__global__ void pack_w(const float* __restrict__ Wih0, const float* __restrict__ Whh0,
                       const float* __restrict__ Wih1, const float* __restrict__ Whh1,
                       int4* __restrict__ ws)
{
    int fid = blockIdx.x * 256 + threadIdx.x;
    if (fid >= F_TOTAL) return;
    const float* src; int nks; int rb;
    if (fid < F_WHH1)      { src = Whh0; nks = 4; rb = fid; }
    else if (fid < F_WIH1) { src = Whh1; nks = 4; rb = fid - F_WHH1; }
    else if (fid < F_WIH0) { src = Wih1; nks = 4; rb = fid - F_WIH1; }
    else                   { src = Wih0; nks = 2; rb = fid - F_WIH0; }
    int lane = rb & 63;
    int rem  = rb >> 6;
    int s    = rem % nks;
    int t    = (rem / nks) & 3;
    int w    = rem / (nks * 4);
    int row  = t * 128 + w * 16 + (lane & 15);   // gate-major
    int K    = nks * 32;
    int k0   = s * 32 + (lane >> 4) * 8;
    const float* p = src + (size_t)row * K + k0;
    unsigned short us[8];
    #pragma unroll
    for (int j = 0; j < 8; ++j)
        us[j] = __builtin_bit_cast(unsigned short, (_Float16)p[j]);  // RNE
    int4 o;
    o.x = (int)((unsigned)us[0] | ((unsigned)us[1] << 16));
    o.y = (int)((unsigned)us[2] | ((unsigned)us[3] << 16));
    o.z = (int)((unsigned)us[4] | ((unsigned)us[5] << 16));
    o.w = (int)((unsigned)us[6] | ((unsigned)us[7] << 16));
    ws[fid] = o;
}

// ---------------- main persistent kernel -----------------------------------
__global__ __launch_bounds__(512, 2)
void lstm_mfma(const float* __restrict__ x,
               const float* __restrict__ bih0, const float* __restrict__ bhh0,
               const float* __restrict__ bih1, const float* __restrict__ bhh1,
               const float* __restrict__ Wlin, const float* __restrict__ blin,
               const int4* __restrict__ ws,
               float* __restrict__ out)
{
    const int b    = blockIdx.x;
    const int tid  = threadIdx.x;
    const int lane = tid & 63;
    const int w    = tid >> 6;
    const int lm   = lane & 15;
    const int lk   = lane >> 4;

    __shared__ __align__(16) int4     Wl1[8][15][64];      // 122,880 B
    __shared__ __align__(16) float    xp0[TC][G4];         //  16,384 B
    __shared__ __align__(16) float    xp1[TC][G4];         //  16,384 B
    __shared__ __align__(16) _Float16 h0_hi[TC+1][HH];     //   2,304 B
    __shared__ __align__(16) _Float16 h0_lo[TC+1][HH];     //   2,304 B
    __shared__ __align__(16) _Float16 h1_hi[2][HH];        //     512 B
    __shared__ __align__(16) _Float16 h1_lo[2][HH];        //     512 B
    // total 161,280 B <= 163,840

    const int  gsel = lm >> 2;                 // this lane's gate (0..3)
    const int  usel = lm & 3;
    const int  u    = w*16 + lk*4 + usel;      // unit owned
    const int  xpr  = gsel*128 + w*16 + lk*4 + usel;
    const int  base = lane & 0x33;             // zero gate bits [3:2]
    const bool writer = (gsel == 0);
    const bool is_g   = (gsel == 2);
    const bool odd    = (lane & 1);            // odd col = lo-term column

    if (tid < HH){
        h0_hi[0][tid] = (_Float16)0.f; h0_lo[0][tid] = (_Float16)0.f;
        h1_hi[0][tid] = (_Float16)0.f; h1_lo[0][tid] = (_Float16)0.f;
    }
    // stage Whh1 frags 1..15 into LDS (once; frag fid = t4*4+s-1)
    #pragma unroll
    for (int f = 0; f < 15; ++f){
        int t4s = f + 1;
        Wl1[w][f][lane] =
            ws[F_WHH1 + (((w*4 + (t4s>>2))*4 + (t4s&3)) << 6) + lane];
    }
    float c0 = 0.f, c1 = 0.f;
    const float* xb = x + (size_t)b * TSEQ * II;
    __syncthreads();

    #pragma unroll 1
    for (int ch = 0; ch <= NCH; ++ch){
        const bool l0 = (ch < NCH);
        const bool l1 = (ch > 0);

        // ---- proj xp1 from prev chunk's h0 (slots 1..8) ----
        if (l1){
            f32x4 acc[4], accL[4];
            #pragma unroll
            for (int t4 = 0; t4 < 4; ++t4){
                acc[t4]  = (f32x4){0.f,0.f,0.f,0.f};
                accL[t4] = (f32x4){0.f,0.f,0.f,0.f};
            }
            int hr = (lm < 8 ? lm : 7) + 1;
            #pragma unroll
            for (int s = 0; s < 4; ++s){
                f16x8 bh = ldb(&h0_hi[hr][s*32 + lk*8]);
                f16x8 bl = ldb(&h0_lo[hr][s*32 + lk*8]);
                int4 ah[4];
                #pragma unroll
                for (int t4 = 0; t4 < 4; ++t4)
                    ah[t4] = ws[F_WIH1 + (((w*4 + t4)*4 + s) << 6) + lane];
                #pragma unroll
                for (int t4 = 0; t4 < 4; ++t4) acc[t4]  = mfma16(ah[t4], bh, acc[t4]);
                #pragma unroll
                for (int t4 = 0; t4 < 4; ++t4) accL[t4] = mfma16(ah[t4], bl, accL[t4]);
            }
            if (lm < 8){
                #pragma unroll
                for (int t4 = 0; t4 < 4; ++t4){
                    int rowb = t4*128 + w*16 + lk*4;
                    f32x4 bs = *(const f32x4*)(bih1 + rowb) + *(const f32x4*)(bhh1 + rowb);
                    *(f32x4*)&xp1[lm][rowb] = acc[t4] + accL[t4]*SCL + bs;
                }
            }
        }
        // ---- carry h0 (slot 0 <- slot 8); disjoint from proj-xp1 reads ----
        if (l0 && ch > 0 && tid < HH){
            h0_hi[0][tid] = h0_hi[TC][tid];
            h0_lo[0][tid] = h0_lo[TC][tid];
        }
        // ---- proj xp0 from global x (B-operand built in-reg) ----
        if (l0){
            int trow = ch*TC + lm; if (trow > TSEQ-1) trow = TSEQ-1;
            const float* xr = xb + (size_t)trow * II;
            f32x4 acc[4], accL[4];
            #pragma unroll
            for (int t4 = 0; t4 < 4; ++t4){
                acc[t4]  = (f32x4){0.f,0.f,0.f,0.f};
                accL[t4] = (f32x4){0.f,0.f,0.f,0.f};
            }
            #pragma unroll
            for (int s = 0; s < 2; ++s){
                float4 va = *(const float4*)(xr + s*32 + lk*8);
                float4 vb = *(const float4*)(xr + s*32 + lk*8 + 4);
                float vv[8] = {va.x,va.y,va.z,va.w,vb.x,vb.y,vb.z,vb.w};
                f16x8 bh, bl;
                #pragma unroll
                for (int j = 0; j < 8; ++j){
                    _Float16 hi = (_Float16)vv[j];
                    bh[j] = hi;
                    bl[j] = (_Float16)((vv[j] - (float)hi)*SCLI);
                }
                int4 ah[4];
                #pragma unroll
                for (int t4 = 0; t4 < 4; ++t4)
                    ah[t4] = ws[F_WIH0 + (((w*4 + t4)*2 + s) << 6) + lane];
                #pragma unroll
                for (int t4 = 0; t4 < 4; ++t4) acc[t4]  = mfma16(ah[t4], bh, acc[t4]);
                #pragma unroll
                for (int t4 = 0; t4 < 4; ++t4) accL[t4] = mfma16(ah[t4], bl, accL[t4]);
            }
            if (lm < 8){
                #pragma unroll
                for (int t4 = 0; t4 < 4; ++t4){
                    int rowb = t4*128 + w*16 + lk*4;
                    f32x4 bs = *(const f32x4*)(bih0 + rowb) + *(const f32x4*)(bhh0 + rowb);
                    *(f32x4*)&xp0[lm][rowb] = acc[t4] + accL[t4]*SCL + bs;
                }
            }
        }
        __syncthreads();

        // ---- per-chunk weight regs: Whh0 16 frags + Whh1 frag(0,0) ----
        int4 Ahi0[4][4], Al1_00;
        if (l0 || l1){
            #pragma unroll
            for (int t4 = 0; t4 < 4; ++t4)
                #pragma unroll
                for (int s = 0; s < 4; ++s)
                    Ahi0[t4][s] = ws[F_WHH0 + (((w*4 + t4)*4 + s) << 6) + lane];
            Al1_00 = ws[F_WHH1 + (((w*4 + 0)*4 + 0) << 6) + lane];
            #pragma unroll
            for (int t4 = 0; t4 < 4; ++t4)
                #pragma unroll
                for (int s = 0; s < 4; ++s) KEEP4I(Ahi0[t4][s]);
            KEEP4I(Al1_00);
        }

        // ---- serial pair loop: L0 step t (chunk ch) + L1 step t (chunk ch-1) ----
        #pragma unroll 1
        for (int t = 0; t < TC; ++t){
            // ================= L0 half =================
            if (l0){
                const _Float16* bp = odd ? &h0_lo[t][0] : &h0_hi[t][0];
                float xpv = xp0[t][xpr];
                f32x4 acc[4];
                #pragma unroll
                for (int t4 = 0; t4 < 4; ++t4) acc[t4] = (f32x4){0.f,0.f,0.f,0.f};
                #pragma unroll
                for (int s = 0; s < 4; ++s){
                    f16x8 bv = ldb(&bp[s*32 + lk*8]);
                    #pragma unroll
                    for (int t4 = 0; t4 < 4; ++t4) acc[t4] = mfma16(Ahi0[t4][s], bv, acc[t4]);
                }
                f32x4 ps;
                {
                    f32x4 p01 = (gsel & 1) ? acc[1] : acc[0];
                    f32x4 p23 = (gsel & 1) ? acc[3] : acc[2];
                    ps = (gsel & 2) ? p23 : p01;
                }
                float own, oth;
                {
                    float a01 = (usel & 1) ? ps[1] : ps[0];
                    float a23 = (usel & 1) ? ps[3] : ps[2];
                    own = (usel & 2) ? a23 : a01;
                    float b01 = (usel & 1) ? ps[0] : ps[1];
                    float b23 = (usel & 1) ? ps[2] : ps[3];
                    oth = (usel & 2) ? b23 : b01;
                }
                float recv = __shfl_xor(oth, 1);
                float pre  = (odd ? (recv + SCL*own) : (own + SCL*recv)) + xpv;
                float z    = tanh_f(is_g ? pre : 0.5f*pre);
                float y    = is_g ? z : 0.5f*z + 0.5f;
                float gi = __shfl(y, base);
                float gf = __shfl(y, base | 4);
                float gg = __shfl(y, base | 8);
                float go = __shfl(y, base | 12);
                c0 = gf*c0 + gi*gg;
                float h = go * tanh_f(c0);
                _Float16 hf = (_Float16)h;
                _Float16 hl = (_Float16)((h - (float)hf) * SCLI);
                if (writer){ h0_hi[t+1][u] = hf; h0_lo[t+1][u] = hl; }
            }
            // ================= L1 half (independent of L0 half) =================
            if (l1){
                const _Float16* bp1 = odd ? &h1_lo[t&1][0] : &h1_hi[t&1][0];
                float xpv1 = xp1[t][xpr];
                f32x4 acc[4];
                #pragma unroll
                for (int t4 = 0; t4 < 4; ++t4) acc[t4] = (f32x4){0.f,0.f,0.f,0.f};
                #pragma unroll
                for (int s = 0; s < 4; ++s){
                    f16x8 bv = ldb(&bp1[s*32 + lk*8]);
                    int4 f0 = (s == 0) ? Al1_00 : Wl1[w][s-1][lane];
                    int4 f1 = Wl1[w][s+3][lane];
                    int4 f2 = Wl1[w][s+7][lane];
                    int4 f3 = Wl1[w][s+11][lane];
                    acc[0] = mfma16(f0, bv, acc[0]);
                    acc[1] = mfma16(f1, bv, acc[1]);
                    acc[2] = mfma16(f2, bv, acc[2]);
                    acc[3] = mfma16(f3, bv, acc[3]);
                    __builtin_amdgcn_sched_barrier(0);  // cap frag inflight (reg budget)
                }
                f32x4 ps;
                {
                    f32x4 p01 = (gsel & 1) ? acc[1] : acc[0];
                    f32x4 p23 = (gsel & 1) ? acc[3] : acc[2];
                    ps = (gsel & 2) ? p23 : p01;
                }
                float own, oth;
                {
                    float a01 = (usel & 1) ? ps[1] : ps[0];
                    float a23 = (usel & 1) ? ps[3] : ps[2];
                    own = (usel & 2) ? a23 : a01;
                    float b01 = (usel & 1) ? ps[0] : ps[1];
                    float b23 = (usel & 1) ? ps[2] : ps[3];
                    oth = (usel & 2) ? b23 : b01;
                }
                float recv = __shfl_xor(oth, 1);
                float pre  = (odd ? (recv + SCL*own) : (own + SCL*recv)) + xpv1;
                float z    = tanh_f(is_g ? pre : 0.5f*pre);
                float y    = is_g ? z : 0.5f*z + 0.5f;
                float gi = __shfl(y, base);
                float gf = __shfl(y, base | 4);
                float gg = __shfl(y, base | 8);
                float go = __shfl(y, base | 12);
                c1 = gf*c1 + gi*gg;
                float h = go * tanh_f(c1);
                _Float16 hf = (_Float16)h;
                _Float16 hl = (_Float16)((h - (float)hf) * SCLI);
                if (writer){ h1_hi[(t+1)&1][u] = hf; h1_lo[(t+1)&1][u] = hl; }
            }
            __syncthreads();   // single barrier per PAIR
        }
    }

    // ---- final linear: h1 final lives in ring slot (TC)&1 = 0 ----
    if (tid < 64){
        float ha = (float)h1_hi[0][tid]    + (float)h1_lo[0][tid]    * SCL;
        float hb = (float)h1_hi[0][tid+64] + (float)h1_lo[0][tid+64] * SCL;
        float s = ha*Wlin[tid] + hb*Wlin[tid+64];
        #pragma unroll
        for (int off = 32; off; off >>= 1) s += __shfl_down(s, off);
        if (tid == 0) out[b] = s + blin[0];
    }
}

extern "C" void kernel_launch(void* const* d_in, const int* in_sizes, int n_in,
                              void* d_out, int out_size, void* d_ws, size_t ws_size,
                              hipStream_t stream)
{
    const float* x    = (const float*)d_in[0];
    const float* Wih0 = (const float*)d_in[1];
    const float* Whh0 = (const float*)d_in[2];
    const float* bih0 = (const float*)d_in[3];
    const float* bhh0 = (const float*)d_in[4];
    const float* Wih1 = (const float*)d_in[5];
    const float* Whh1 = (const float*)d_in[6];
    const float* bih1 = (const float*)d_in[7];
    const float* bhh1 = (const float*)d_in[8];
    const float* Wlin = (const float*)d_in[9];
    const float* blin = (const float*)d_in[10];
    int4* ws = (int4*)d_ws;   // requires ws_size >= 458,752 B

    hipLaunchKernelGGL(pack_w, dim3(F_TOTAL/256), dim3(256), 0, stream,
                       Wih0, Whh0, Wih1, Whh1, ws);
    hipLaunchKernelGGL(lstm_mfma, dim3(NB), dim3(512), 0, stream,
                       x, bih0, bhh0, bih1, bhh1, Wlin, blin, ws, (float*)d_out);
}